// Round 4
// baseline (430.666 us; speedup 1.0000x reference)
//
#include <hip/hip_runtime.h>
#include <hip/hip_bf16.h>
#include <cstdint>

#define NH 4
#define HC 128     // H*C
#define INCH 128
#define NEDGE 500000
#define NN 100000

// multisplit geometry
#define KE_SHIFT 11            // 2048 edges per bucket
#define KV_SHIFT 9             // 512 vertices per bucket
#define KE (1 << KE_SHIFT)
#define KV (1 << KV_SHIFT)
#define NBE 245                // ceil(500000/2048)
#define NBV 196                // ceil(100000/512)
#define CAP_E 8192             // mean 6554, +20 sigma
#define CAP_V 10240            // mean 8192, +22 sigma
#define CHUNK_A 8192

typedef float        f32x4 __attribute__((ext_vector_type(4)));
typedef unsigned int u32x2 __attribute__((ext_vector_type(2)));
typedef int          i32x2 __attribute__((ext_vector_type(2)));

static __device__ __forceinline__ unsigned short f2bf(float f){
  union { float f; unsigned u; } v; v.f = f;
  unsigned r = v.u + 0x7fffu + ((v.u >> 16) & 1u);
  return (unsigned short)(r >> 16);
}
static __device__ __forceinline__ float bf2f(unsigned short b){
  union { unsigned u; float f; } v; v.u = ((unsigned)b) << 16;
  return v.f;
}
static __device__ __forceinline__ f32x4 bf4f(ushort4 b){
  f32x4 r; r.x=bf2f(b.x); r.y=bf2f(b.y); r.z=bf2f(b.z); r.w=bf2f(b.w); return r;
}
static __device__ __forceinline__ void nt_store_bf4(unsigned short* p, ushort4 v){
  u32x2 w; w.x = (unsigned)v.x | ((unsigned)v.y<<16); w.y = (unsigned)v.z | ((unsigned)v.w<<16);
  __builtin_nontemporal_store(w, (u32x2*)p);
}

// ---------------- X0 = X @ W (f32, exact) + bf16 copy + exact att-score ----------------
#define GBM 128
#define GBK 16
__global__ __launch_bounds__(256) void gemm_x0(const float* __restrict__ X,
                                               const float* __restrict__ Wm,
                                               const float* __restrict__ att,
                                               float* __restrict__ X0,
                                               unsigned short* __restrict__ X0bf,
                                               float* __restrict__ score, int nrows){
  __shared__ float As[GBK][GBM+4];
  __shared__ float Bs[GBK][HC+4];
  __shared__ float sc[GBM][17];
  const int tid  = threadIdx.x;
  const int row0 = blockIdx.x * GBM;
  const int trow = tid >> 4;   // 0..15
  const int tcol = tid & 15;   // 0..15
  float acc[8][8];
  #pragma unroll
  for (int i=0;i<8;i++)
    #pragma unroll
    for (int j=0;j<8;j++) acc[i][j]=0.f;

  for (int k0=0;k0<INCH;k0+=GBK){
    #pragma unroll
    for (int l = tid; l < 512; l += 256){
      int r  = l >> 2;
      int ks = (l & 3) * 4;
      int grow = row0 + r;
      float4 v = make_float4(0.f,0.f,0.f,0.f);
      if (grow < nrows) v = *(const float4*)(X + (size_t)grow*INCH + k0 + ks);
      As[ks+0][r]=v.x; As[ks+1][r]=v.y; As[ks+2][r]=v.z; As[ks+3][r]=v.w;
    }
    #pragma unroll
    for (int l = tid; l < 512; l += 256){
      int r  = l >> 5;
      int cs = (l & 31) * 4;
      float4 v = *(const float4*)(Wm + (size_t)(k0+r)*HC + cs);
      *(float4*)(&Bs[r][cs]) = v;
    }
    __syncthreads();
    #pragma unroll
    for (int kk=0;kk<GBK;kk++){
      float a[8], b[8];
      *(float4*)&a[0] = *(float4*)&As[kk][trow*8];
      *(float4*)&a[4] = *(float4*)&As[kk][trow*8+4];
      *(float4*)&b[0] = *(float4*)&Bs[kk][tcol*8];
      *(float4*)&b[4] = *(float4*)&Bs[kk][tcol*8+4];
      #pragma unroll
      for (int i=0;i<8;i++)
        #pragma unroll
        for (int j=0;j<8;j++) acc[i][j] = fmaf(a[i], b[j], acc[i][j]);
    }
    __syncthreads();
  }
  float attv[8];
  *(float4*)&attv[0] = *(const float4*)(att + tcol*8);
  *(float4*)&attv[4] = *(const float4*)(att + tcol*8 + 4);
  #pragma unroll
  for (int i=0;i<8;i++){
    int grow = row0 + trow*8 + i;
    float p = 0.f;
    #pragma unroll
    for (int j=0;j<8;j++) p = fmaf(acc[i][j], attv[j], p);
    sc[trow*8+i][tcol] = p;
    if (grow < nrows){
      f32x4 o0 = { acc[i][0],acc[i][1],acc[i][2],acc[i][3] };
      f32x4 o1 = { acc[i][4],acc[i][5],acc[i][6],acc[i][7] };
      // nt: X0 is only read (streaming) by vert_pass much later — keep out of L3
      __builtin_nontemporal_store(o0, (f32x4*)(X0 + (size_t)grow*HC + tcol*8));
      __builtin_nontemporal_store(o1, (f32x4*)(X0 + (size_t)grow*HC + tcol*8 + 4));
      ushort4 b0, b1;
      b0.x=f2bf(acc[i][0]); b0.y=f2bf(acc[i][1]); b0.z=f2bf(acc[i][2]); b0.w=f2bf(acc[i][3]);
      b1.x=f2bf(acc[i][4]); b1.y=f2bf(acc[i][5]); b1.z=f2bf(acc[i][6]); b1.w=f2bf(acc[i][7]);
      *(ushort4*)(X0bf + (size_t)grow*HC + tcol*8    ) = b0;   // cached: edge_agg gathers this
      *(ushort4*)(X0bf + (size_t)grow*HC + tcol*8 + 4) = b1;
    }
  }
  __syncthreads();
  for (int idx = tid; idx < GBM*NH; idx += 256){
    int row = idx >> 2, h = idx & 3;
    int grow = row0 + row;
    if (grow < nrows){
      float s = sc[row][4*h] + sc[row][4*h+1] + sc[row][4*h+2] + sc[row][4*h+3];
      score[(size_t)grow*NH + h] = s;     // cached: tiny + reused
    }
  }
}

// ---------------- CSR build: two-phase LDS-binned multisplit ----------------
__global__ void init_curs(int* __restrict__ cursE, int* __restrict__ cursV){
  int t = threadIdx.x;
  if (t < NBE) cursE[t] = t * CAP_E;
  if (t < NBV) cursV[t] = t * CAP_V;
}

__global__ __launch_bounds__(512) void phaseA(const int* __restrict__ vertex,
                                              const int* __restrict__ edges, int nnz,
                                              int* __restrict__ cursE, int* __restrict__ cursV,
                                              int2* __restrict__ stgE, int2* __restrict__ stgV){
  __shared__ int cE[NBE], c2E[NBE], gE[NBE];
  __shared__ int cV[NBV], c2V[NBV], gV[NBV];
  const int t = threadIdx.x;
  const int base = blockIdx.x * CHUNK_A;
  int ev[16], vv[16];
  #pragma unroll
  for (int j=0;j<16;j++){
    int i = base + t + j*512;
    if (i < nnz){ ev[j] = edges[i]; vv[j] = vertex[i]; }
    else ev[j] = -1;
  }
  for (int j=t;j<NBE;j+=512){ cE[j]=0; c2E[j]=0; }
  for (int j=t;j<NBV;j+=512){ cV[j]=0; c2V[j]=0; }
  __syncthreads();
  #pragma unroll
  for (int j=0;j<16;j++) if (ev[j]>=0){
    atomicAdd(&cE[ev[j]>>KE_SHIFT], 1);
    atomicAdd(&cV[vv[j]>>KV_SHIFT], 1);
  }
  __syncthreads();
  for (int j=t;j<NBE;j+=512) gE[j] = atomicAdd(&cursE[j], cE[j]);
  for (int j=t;j<NBV;j+=512) gV[j] = atomicAdd(&cursV[j], cV[j]);
  __syncthreads();
  #pragma unroll
  for (int j=0;j<16;j++) if (ev[j]>=0){
    int bE = ev[j]>>KE_SHIFT;
    int p = gE[bE] + atomicAdd(&c2E[bE],1);
    if (p < (bE+1)*CAP_E){ i32x2 w = { ev[j], vv[j] }; __builtin_nontemporal_store(w, (i32x2*)&stgE[p]); }
    int bV = vv[j]>>KV_SHIFT;
    int q = gV[bV] + atomicAdd(&c2V[bV],1);
    if (q < (bV+1)*CAP_V){ i32x2 w = { vv[j], ev[j] }; __builtin_nontemporal_store(w, (i32x2*)&stgV[q]); }
  }
}

__global__ __launch_bounds__(512) void bucket_scan(const int* __restrict__ cursE,
                                                   const int* __restrict__ cursV,
                                                   int* __restrict__ baseE, int* __restrict__ baseV,
                                                   int* __restrict__ eoffs, int* __restrict__ voffs,
                                                   int nnz){
  __shared__ int sh[512];
  const int t = threadIdx.x;
  int v = (t < NBE) ? (cursE[t] - t*CAP_E) : 0;
  sh[t] = v; __syncthreads();
  for (int d2=1; d2<512; d2<<=1){
    int x = (t>=d2) ? sh[t-d2] : 0; __syncthreads();
    sh[t] += x; __syncthreads();
  }
  if (t < NBE) baseE[t] = sh[t] - v;
  __syncthreads();
  int v2 = (t < NBV) ? (cursV[t] - t*CAP_V) : 0;
  sh[t] = v2; __syncthreads();
  for (int d2=1; d2<512; d2<<=1){
    int x = (t>=d2) ? sh[t-d2] : 0; __syncthreads();
    sh[t] += x; __syncthreads();
  }
  if (t < NBV) baseV[t] = sh[t] - v2;
  if (t == 0){ eoffs[NEDGE] = nnz; voffs[NN] = nnz; }
}

template<int K, int CAP, int IT>
__global__ __launch_bounds__(512) void phaseB_k(const int2* __restrict__ stg,
                                                const int* __restrict__ curs,
                                                const int* __restrict__ bbase,
                                                int* __restrict__ offsOut,
                                                int* __restrict__ csrOut, int nKeys){
  __shared__ int cur[K];
  __shared__ int tsum[512];
  const int b = blockIdx.x, t = threadIdx.x;
  const int k0 = b * K;
  const int kc = min(K, nKeys - k0);
  int cnt = curs[b] - b*CAP; cnt = min(cnt, CAP);
  const int gbase = bbase[b];
  int2 it[IT];
  #pragma unroll
  for (int j=0;j<IT;j++){
    int i = t + j*512;
    it[j] = (i < cnt) ? stg[(size_t)b*CAP + i] : make_int2(-1,0);
  }
  for (int j=t;j<K;j+=512) cur[j] = 0;
  __syncthreads();
  #pragma unroll
  for (int j=0;j<IT;j++) if (it[j].x >= 0) atomicAdd(&cur[it[j].x - k0], 1);
  __syncthreads();
  constexpr int KPT = K / 512;
  int loc[KPT]; int s = 0;
  #pragma unroll
  for (int j=0;j<KPT;j++){ loc[j] = s; s += cur[t*KPT + j]; }
  tsum[t] = s; __syncthreads();
  for (int d2=1; d2<512; d2<<=1){
    int x = (t>=d2) ? tsum[t-d2] : 0; __syncthreads();
    tsum[t] += x; __syncthreads();
  }
  const int tbase = tsum[t] - s;
  __syncthreads();
  #pragma unroll
  for (int j=0;j<KPT;j++){
    int k = t*KPT + j;
    int abs0 = gbase + tbase + loc[j];
    if (k < kc) offsOut[k0 + k] = abs0;
    cur[k] = abs0;
  }
  __syncthreads();
  #pragma unroll
  for (int j=0;j<IT;j++) if (it[j].x >= 0){
    int pos = atomicAdd(&cur[it[j].x - k0], 1);
    csrOut[pos] = it[j].y;
  }
}

// ---------------- per-edge: bf16 mean + exact score-mean attention, unroll 2 ----------------
__global__ __launch_bounds__(256) void edge_agg(const unsigned short* __restrict__ X0bf,
                                                const float* __restrict__ score,
                                                const int* __restrict__ ecsr,
                                                const int* __restrict__ eoffs,
                                                unsigned short* __restrict__ Xe,
                                                float* __restrict__ alphaE, int E){
  int eg = blockIdx.x * 8 + (threadIdx.x >> 5);
  if (eg >= E) return;
  const int lane  = threadIdx.x & 31;
  const int cbase = lane * 4;
  const int start = eoffs[eg];
  const int d     = eoffs[eg+1] - start;
  f32x4 acc0 = {0.f,0.f,0.f,0.f}, acc1 = {0.f,0.f,0.f,0.f};
  float sacc0 = 0.f, sacc1 = 0.f;
  int k = 0;
  for (; k+1<d; k+=2){
    int v0 = ecsr[start + k];
    int v1 = ecsr[start + k + 1];
    ushort4 xb0 = *(const ushort4*)(X0bf + (size_t)v0*HC + cbase);
    ushort4 xb1 = *(const ushort4*)(X0bf + (size_t)v1*HC + cbase);
    if (lane < NH){
      sacc0 += score[(size_t)v0*NH + lane];
      sacc1 += score[(size_t)v1*NH + lane];
    }
    acc0 += bf4f(xb0);
    acc1 += bf4f(xb1);
  }
  if (k < d){
    int v0 = ecsr[start + k];
    ushort4 xb0 = *(const ushort4*)(X0bf + (size_t)v0*HC + cbase);
    if (lane < NH) sacc0 += score[(size_t)v0*NH + lane];
    acc0 += bf4f(xb0);
  }
  acc0 += acc1;
  const float inv = 1.0f / fmaxf((float)d, 1.0f);
  acc0 *= inv;
  ushort4 xb;
  xb.x = f2bf(acc0.x); xb.y = f2bf(acc0.y); xb.z = f2bf(acc0.z); xb.w = f2bf(acc0.w);
  nt_store_bf4(Xe + (size_t)eg*HC + cbase, xb);       // nt: don't evict X0bf/score
  if (lane < NH){
    float a = (sacc0 + sacc1) * inv;
    a = a > 0.f ? a : 0.01f*a;                        // leaky relu
    __builtin_nontemporal_store(a, alphaE + (size_t)eg*NH + lane);
  }
}

// ---------------- per-vertex: two-phase softmax (parallel m/den, pipelined sum) ----------------
__global__ __launch_bounds__(256) void vert_pass(const float* __restrict__ X0,
                                                 const unsigned short* __restrict__ Xe,
                                                 const float* __restrict__ alphaE,
                                                 const int* __restrict__ vcsr,
                                                 const int* __restrict__ voffs,
                                                 float* __restrict__ out, int N){
  int n = blockIdx.x * 8 + (threadIdx.x >> 5);
  if (n >= N) return;
  const int lane  = threadIdx.x & 31;
  const int cbase = lane * 4;
  const int h     = lane >> 3;   // head for this lane's channel quad
  const int j0    = lane & 7;    // phase-1 edge slot
  const size_t obase = (size_t)n*HC + cbase;
  f32x4 x0 = __builtin_nontemporal_load((const f32x4*)(X0 + obase));
  const int start = voffs[n];
  const int d     = voffs[n+1] - start;
  if (d == 0){ __builtin_nontemporal_store(x0, (f32x4*)(out + obase)); return; }

  // phase 1: 8 lanes per head process edges j0, j0+8, ... in parallel
  float m = -1e30f, den = 0.f;
  for (int j=j0; j<d; j+=8){
    int e = vcsr[start + j];
    float a = alphaE[(size_t)e*NH + h];
    float mn = fmaxf(m, a);
    den = den*__expf(m - mn) + __expf(a - mn);
    m = mn;
  }
  #pragma unroll
  for (int s=1; s<8; s<<=1){
    float mo = __shfl_xor(m, s, 8);
    float dn = __shfl_xor(den, s, 8);
    float mn = fmaxf(m, mo);
    den = den*__expf(m - mn) + dn*__expf(mo - mn);
    m = mn;
  }
  const float w = 1.0f / (den + 1e-16f);

  // phase 2: weighted gather with precomputed (m, w) — independent chains, unroll 2
  f32x4 acc0 = {0.f,0.f,0.f,0.f}, acc1 = {0.f,0.f,0.f,0.f};
  int k = 0;
  for (; k+1<d; k+=2){
    int e0 = vcsr[start + k];
    int e1 = vcsr[start + k + 1];
    float a0 = alphaE[(size_t)e0*NH + h];
    float a1 = alphaE[(size_t)e1*NH + h];
    ushort4 b0 = *(const ushort4*)(Xe + (size_t)e0*HC + cbase);
    ushort4 b1 = *(const ushort4*)(Xe + (size_t)e1*HC + cbase);
    float w0 = __expf(a0 - m) * w;
    float w1 = __expf(a1 - m) * w;
    acc0 += w0 * bf4f(b0);
    acc1 += w1 * bf4f(b1);
  }
  if (k < d){
    int e0 = vcsr[start + k];
    float a0 = alphaE[(size_t)e0*NH + h];
    ushort4 b0 = *(const ushort4*)(Xe + (size_t)e0*HC + cbase);
    acc0 += (__expf(a0 - m) * w) * bf4f(b0);
  }
  acc0 += acc1;
  acc0 += x0;
  __builtin_nontemporal_store(acc0, (f32x4*)(out + obase));
}

extern "C" void kernel_launch(void* const* d_in, const int* in_sizes, int n_in,
                              void* d_out, int out_size, void* d_ws, size_t ws_size,
                              hipStream_t stream){
  const float* X   = (const float*)d_in[0];
  const float* Wm  = (const float*)d_in[1];
  const float* att = (const float*)d_in[2];
  const int* vertex = (const int*)d_in[3];
  const int* edges  = (const int*)d_in[4];
  const int N   = in_sizes[0] / INCH;
  const int NNZ = in_sizes[3];
  const int E   = NEDGE;

  float* X0 = (float*)d_out;   // d_out doubles as X0 (written by gemm, consumed, then overwritten)

  char* ws = (char*)d_ws;
  size_t off = 0;
  auto alloc = [&](size_t bytes)->char*{
    char* p = ws + off;
    off += (bytes + 255) & ~(size_t)255;
    return p;
  };
  unsigned short* Xe     = (unsigned short*)alloc((size_t)E * HC * sizeof(unsigned short)); // 128 MB
  unsigned short* X0bf   = (unsigned short*)alloc((size_t)NN * HC * sizeof(unsigned short)); // 25.6 MB
  float*          score  = (float*)alloc((size_t)NN * NH * sizeof(float));                  // 1.6 MB
  float*          alphaE = (float*)alloc((size_t)E * NH * sizeof(float));
  int*            eoffs  = (int*)alloc((size_t)(E+1) * sizeof(int));
  int*            voffs  = (int*)alloc((size_t)(NN+1) * sizeof(int));
  int*            ecsr   = (int*)alloc((size_t)NNZ * sizeof(int));
  int*            vcsr   = (int*)alloc((size_t)NNZ * sizeof(int));
  int*            cursE  = (int*)alloc(NBE * sizeof(int));
  int*            cursV  = (int*)alloc(NBV * sizeof(int));
  int*            baseE  = (int*)alloc(NBE * sizeof(int));
  int*            baseV  = (int*)alloc(NBV * sizeof(int));
  // staging aliases Xe (dead until edge_agg runs, which is after phase B)
  int2* stgE = (int2*)(void*)Xe;
  int2* stgV = (int2*)((char*)(void*)Xe + (size_t)NBE * CAP_E * sizeof(int2));

  gemm_x0<<<(N + GBM - 1)/GBM, 256, 0, stream>>>(X, Wm, att, X0, X0bf, score, N);
  init_curs<<<1, 512, 0, stream>>>(cursE, cursV);
  phaseA<<<(NNZ + CHUNK_A - 1)/CHUNK_A, 512, 0, stream>>>(vertex, edges, NNZ, cursE, cursV, stgE, stgV);
  bucket_scan<<<1, 512, 0, stream>>>(cursE, cursV, baseE, baseV, eoffs, voffs, NNZ);
  phaseB_k<KE, CAP_E, CAP_E/512><<<NBE, 512, 0, stream>>>(stgE, cursE, baseE, eoffs, ecsr, E);
  phaseB_k<KV, CAP_V, CAP_V/512><<<NBV, 512, 0, stream>>>(stgV, cursV, baseV, voffs, vcsr, NN);
  edge_agg<<<(E + 7)/8, 256, 0, stream>>>(X0bf, score, ecsr, eoffs, Xe, alphaE, E);
  vert_pass<<<(N + 7)/8, 256, 0, stream>>>(X0, Xe, alphaE, vcsr, voffs, (float*)d_out, N);
}

// Round 5
// 331.997 us; speedup vs baseline: 1.2972x; 1.2972x over previous
//
#include <hip/hip_runtime.h>
#include <hip/hip_bf16.h>
#include <cstdint>

#define NH 4
#define HC 128     // H*C
#define INCH 128
#define NEDGE 500000
#define NN 100000

// multisplit geometry
#define KE_SHIFT 11            // 2048 edges per bucket
#define KV_SHIFT 9             // 512 vertices per bucket
#define KE (1 << KE_SHIFT)
#define KV (1 << KV_SHIFT)
#define NBE 245                // ceil(500000/2048)
#define NBV 196                // ceil(100000/512)
#define CAP_E 8192             // mean 6554, +20 sigma
#define CAP_V 10240            // mean 8192, +22 sigma
#define CHUNK_A 8192

typedef float        f32x4 __attribute__((ext_vector_type(4)));
typedef unsigned int u32x2 __attribute__((ext_vector_type(2)));

static __device__ __forceinline__ unsigned short f2bf(float f){
  union { float f; unsigned u; } v; v.f = f;
  unsigned r = v.u + 0x7fffu + ((v.u >> 16) & 1u);
  return (unsigned short)(r >> 16);
}
static __device__ __forceinline__ float bf2f(unsigned short b){
  union { unsigned u; float f; } v; v.u = ((unsigned)b) << 16;
  return v.f;
}
static __device__ __forceinline__ f32x4 bf4f(ushort4 b){
  f32x4 r; r.x=bf2f(b.x); r.y=bf2f(b.y); r.z=bf2f(b.z); r.w=bf2f(b.w); return r;
}
static __device__ __forceinline__ void nt_store_bf4(unsigned short* p, ushort4 v){
  u32x2 w; w.x = (unsigned)v.x | ((unsigned)v.y<<16); w.y = (unsigned)v.z | ((unsigned)v.w<<16);
  __builtin_nontemporal_store(w, (u32x2*)p);
}

// ---------------- X0bf = bf16(X @ W) + exact att-score (no f32 X0 materialized) ----------------
#define GBM 128
#define GBK 16
__global__ __launch_bounds__(256) void gemm_x0(const float* __restrict__ X,
                                               const float* __restrict__ Wm,
                                               const float* __restrict__ att,
                                               unsigned short* __restrict__ X0bf,
                                               float* __restrict__ score, int nrows){
  __shared__ float As[GBK][GBM+4];
  __shared__ float Bs[GBK][HC+4];
  __shared__ float sc[GBM][17];
  const int tid  = threadIdx.x;
  const int row0 = blockIdx.x * GBM;
  const int trow = tid >> 4;   // 0..15
  const int tcol = tid & 15;   // 0..15
  float acc[8][8];
  #pragma unroll
  for (int i=0;i<8;i++)
    #pragma unroll
    for (int j=0;j<8;j++) acc[i][j]=0.f;

  for (int k0=0;k0<INCH;k0+=GBK){
    #pragma unroll
    for (int l = tid; l < 512; l += 256){
      int r  = l >> 2;
      int ks = (l & 3) * 4;
      int grow = row0 + r;
      float4 v = make_float4(0.f,0.f,0.f,0.f);
      if (grow < nrows) v = *(const float4*)(X + (size_t)grow*INCH + k0 + ks);
      As[ks+0][r]=v.x; As[ks+1][r]=v.y; As[ks+2][r]=v.z; As[ks+3][r]=v.w;
    }
    #pragma unroll
    for (int l = tid; l < 512; l += 256){
      int r  = l >> 5;
      int cs = (l & 31) * 4;
      float4 v = *(const float4*)(Wm + (size_t)(k0+r)*HC + cs);
      *(float4*)(&Bs[r][cs]) = v;
    }
    __syncthreads();
    #pragma unroll
    for (int kk=0;kk<GBK;kk++){
      float a[8], b[8];
      *(float4*)&a[0] = *(float4*)&As[kk][trow*8];
      *(float4*)&a[4] = *(float4*)&As[kk][trow*8+4];
      *(float4*)&b[0] = *(float4*)&Bs[kk][tcol*8];
      *(float4*)&b[4] = *(float4*)&Bs[kk][tcol*8+4];
      #pragma unroll
      for (int i=0;i<8;i++)
        #pragma unroll
        for (int j=0;j<8;j++) acc[i][j] = fmaf(a[i], b[j], acc[i][j]);
    }
    __syncthreads();
  }
  float attv[8];
  *(float4*)&attv[0] = *(const float4*)(att + tcol*8);
  *(float4*)&attv[4] = *(const float4*)(att + tcol*8 + 4);
  #pragma unroll
  for (int i=0;i<8;i++){
    int grow = row0 + trow*8 + i;
    float p = 0.f;
    #pragma unroll
    for (int j=0;j<8;j++) p = fmaf(acc[i][j], attv[j], p);
    sc[trow*8+i][tcol] = p;
    if (grow < nrows){
      ushort4 b0, b1;
      b0.x=f2bf(acc[i][0]); b0.y=f2bf(acc[i][1]); b0.z=f2bf(acc[i][2]); b0.w=f2bf(acc[i][3]);
      b1.x=f2bf(acc[i][4]); b1.y=f2bf(acc[i][5]); b1.z=f2bf(acc[i][6]); b1.w=f2bf(acc[i][7]);
      *(ushort4*)(X0bf + (size_t)grow*HC + tcol*8    ) = b0;   // cached: edge_agg gathers this
      *(ushort4*)(X0bf + (size_t)grow*HC + tcol*8 + 4) = b1;
    }
  }
  __syncthreads();
  for (int idx = tid; idx < GBM*NH; idx += 256){
    int row = idx >> 2, h = idx & 3;
    int grow = row0 + row;
    if (grow < nrows){
      float s = sc[row][4*h] + sc[row][4*h+1] + sc[row][4*h+2] + sc[row][4*h+3];
      score[(size_t)grow*NH + h] = s;     // cached: tiny + reused
    }
  }
}

// ---------------- CSR build: two-phase LDS-binned multisplit ----------------
__global__ void init_curs(int* __restrict__ cursE, int* __restrict__ cursV){
  int t = threadIdx.x;
  if (t < NBE) cursE[t] = t * CAP_E;
  if (t < NBV) cursV[t] = t * CAP_V;
}

__global__ __launch_bounds__(512) void phaseA(const int* __restrict__ vertex,
                                              const int* __restrict__ edges, int nnz,
                                              int* __restrict__ cursE, int* __restrict__ cursV,
                                              int2* __restrict__ stgE, int2* __restrict__ stgV){
  __shared__ int cE[NBE], c2E[NBE], gE[NBE];
  __shared__ int cV[NBV], c2V[NBV], gV[NBV];
  const int t = threadIdx.x;
  const int base = blockIdx.x * CHUNK_A;
  int ev[16], vv[16];
  #pragma unroll
  for (int j=0;j<16;j++){
    int i = base + t + j*512;
    if (i < nnz){ ev[j] = edges[i]; vv[j] = vertex[i]; }
    else ev[j] = -1;
  }
  for (int j=t;j<NBE;j+=512){ cE[j]=0; c2E[j]=0; }
  for (int j=t;j<NBV;j+=512){ cV[j]=0; c2V[j]=0; }
  __syncthreads();
  #pragma unroll
  for (int j=0;j<16;j++) if (ev[j]>=0){
    atomicAdd(&cE[ev[j]>>KE_SHIFT], 1);
    atomicAdd(&cV[vv[j]>>KV_SHIFT], 1);
  }
  __syncthreads();
  for (int j=t;j<NBE;j+=512) gE[j] = atomicAdd(&cursE[j], cE[j]);
  for (int j=t;j<NBV;j+=512) gV[j] = atomicAdd(&cursV[j], cV[j]);
  __syncthreads();
  #pragma unroll
  for (int j=0;j<16;j++) if (ev[j]>=0){
    int bE = ev[j]>>KE_SHIFT;
    int p = gE[bE] + atomicAdd(&c2E[bE],1);
    if (p < (bE+1)*CAP_E) stgE[p] = make_int2(ev[j], vv[j]);
    int bV = vv[j]>>KV_SHIFT;
    int q = gV[bV] + atomicAdd(&c2V[bV],1);
    if (q < (bV+1)*CAP_V) stgV[q] = make_int2(vv[j], ev[j]);
  }
}

__global__ __launch_bounds__(512) void bucket_scan(const int* __restrict__ cursE,
                                                   const int* __restrict__ cursV,
                                                   int* __restrict__ baseE, int* __restrict__ baseV,
                                                   int* __restrict__ eoffs, int* __restrict__ voffs,
                                                   int nnz){
  __shared__ int sh[512];
  const int t = threadIdx.x;
  int v = (t < NBE) ? (cursE[t] - t*CAP_E) : 0;
  sh[t] = v; __syncthreads();
  for (int d2=1; d2<512; d2<<=1){
    int x = (t>=d2) ? sh[t-d2] : 0; __syncthreads();
    sh[t] += x; __syncthreads();
  }
  if (t < NBE) baseE[t] = sh[t] - v;
  __syncthreads();
  int v2 = (t < NBV) ? (cursV[t] - t*CAP_V) : 0;
  sh[t] = v2; __syncthreads();
  for (int d2=1; d2<512; d2<<=1){
    int x = (t>=d2) ? sh[t-d2] : 0; __syncthreads();
    sh[t] += x; __syncthreads();
  }
  if (t < NBV) baseV[t] = sh[t] - v2;
  if (t == 0){ eoffs[NEDGE] = nnz; voffs[NN] = nnz; }
}

template<int K, int CAP, int IT>
__global__ __launch_bounds__(512) void phaseB_k(const int2* __restrict__ stg,
                                                const int* __restrict__ curs,
                                                const int* __restrict__ bbase,
                                                int* __restrict__ offsOut,
                                                int* __restrict__ csrOut, int nKeys){
  __shared__ int cur[K];
  __shared__ int tsum[512];
  const int b = blockIdx.x, t = threadIdx.x;
  const int k0 = b * K;
  const int kc = min(K, nKeys - k0);
  int cnt = curs[b] - b*CAP; cnt = min(cnt, CAP);
  const int gbase = bbase[b];
  int2 it[IT];
  #pragma unroll
  for (int j=0;j<IT;j++){
    int i = t + j*512;
    it[j] = (i < cnt) ? stg[(size_t)b*CAP + i] : make_int2(-1,0);
  }
  for (int j=t;j<K;j+=512) cur[j] = 0;
  __syncthreads();
  #pragma unroll
  for (int j=0;j<IT;j++) if (it[j].x >= 0) atomicAdd(&cur[it[j].x - k0], 1);
  __syncthreads();
  constexpr int KPT = K / 512;
  int loc[KPT]; int s = 0;
  #pragma unroll
  for (int j=0;j<KPT;j++){ loc[j] = s; s += cur[t*KPT + j]; }
  tsum[t] = s; __syncthreads();
  for (int d2=1; d2<512; d2<<=1){
    int x = (t>=d2) ? tsum[t-d2] : 0; __syncthreads();
    tsum[t] += x; __syncthreads();
  }
  const int tbase = tsum[t] - s;
  __syncthreads();
  #pragma unroll
  for (int j=0;j<KPT;j++){
    int k = t*KPT + j;
    int abs0 = gbase + tbase + loc[j];
    if (k < kc) offsOut[k0 + k] = abs0;
    cur[k] = abs0;
  }
  __syncthreads();
  #pragma unroll
  for (int j=0;j<IT;j++) if (it[j].x >= 0){
    int pos = atomicAdd(&cur[it[j].x - k0], 1);
    csrOut[pos] = it[j].y;
  }
}

// ---------------- per-edge: bf16 mean + exact score-mean attention, unroll 2 ----------------
__global__ __launch_bounds__(256) void edge_agg(const unsigned short* __restrict__ X0bf,
                                                const float* __restrict__ score,
                                                const int* __restrict__ ecsr,
                                                const int* __restrict__ eoffs,
                                                unsigned short* __restrict__ Xe,
                                                float* __restrict__ alphaE, int E){
  int eg = blockIdx.x * 8 + (threadIdx.x >> 5);
  if (eg >= E) return;
  const int lane  = threadIdx.x & 31;
  const int cbase = lane * 4;
  const int start = eoffs[eg];
  const int d     = eoffs[eg+1] - start;
  f32x4 acc0 = {0.f,0.f,0.f,0.f}, acc1 = {0.f,0.f,0.f,0.f};
  float sacc0 = 0.f, sacc1 = 0.f;
  int k = 0;
  for (; k+1<d; k+=2){
    int v0 = ecsr[start + k];
    int v1 = ecsr[start + k + 1];
    ushort4 xb0 = *(const ushort4*)(X0bf + (size_t)v0*HC + cbase);
    ushort4 xb1 = *(const ushort4*)(X0bf + (size_t)v1*HC + cbase);
    if (lane < NH){
      sacc0 += score[(size_t)v0*NH + lane];
      sacc1 += score[(size_t)v1*NH + lane];
    }
    acc0 += bf4f(xb0);
    acc1 += bf4f(xb1);
  }
  if (k < d){
    int v0 = ecsr[start + k];
    ushort4 xb0 = *(const ushort4*)(X0bf + (size_t)v0*HC + cbase);
    if (lane < NH) sacc0 += score[(size_t)v0*NH + lane];
    acc0 += bf4f(xb0);
  }
  acc0 += acc1;
  const float inv = 1.0f / fmaxf((float)d, 1.0f);
  acc0 *= inv;
  ushort4 xb;
  xb.x = f2bf(acc0.x); xb.y = f2bf(acc0.y); xb.z = f2bf(acc0.z); xb.w = f2bf(acc0.w);
  nt_store_bf4(Xe + (size_t)eg*HC + cbase, xb);       // nt: don't evict X0bf/score
  if (lane < NH){
    float a = (sacc0 + sacc1) * inv;
    a = a > 0.f ? a : 0.01f*a;                        // leaky relu
    __builtin_nontemporal_store(a, alphaE + (size_t)eg*NH + lane);
  }
}

// ---------------- per-vertex: two-phase softmax, unroll-4 weighted gather ----------------
__global__ __launch_bounds__(256) void vert_pass(const unsigned short* __restrict__ X0bf,
                                                 const unsigned short* __restrict__ Xe,
                                                 const float* __restrict__ alphaE,
                                                 const int* __restrict__ vcsr,
                                                 const int* __restrict__ voffs,
                                                 float* __restrict__ out, int N){
  int n = blockIdx.x * 8 + (threadIdx.x >> 5);
  if (n >= N) return;
  const int lane  = threadIdx.x & 31;
  const int cbase = lane * 4;
  const int h     = lane >> 3;   // head for this lane's channel quad
  const int j0    = lane & 7;    // phase-1 edge slot
  const size_t obase = (size_t)n*HC + cbase;
  ushort4 xr = *(const ushort4*)(X0bf + obase);
  f32x4 x0 = bf4f(xr);
  const int start = voffs[n];
  const int d     = voffs[n+1] - start;
  if (d == 0){ __builtin_nontemporal_store(x0, (f32x4*)(out + obase)); return; }

  // phase 1: 8 lanes per head process edges j0, j0+8, ... in parallel
  float m = -1e30f, den = 0.f;
  for (int j=j0; j<d; j+=8){
    int e = vcsr[start + j];
    float a = alphaE[(size_t)e*NH + h];
    float mn = fmaxf(m, a);
    den = den*__expf(m - mn) + __expf(a - mn);
    m = mn;
  }
  #pragma unroll
  for (int s=1; s<8; s<<=1){
    float mo = __shfl_xor(m, s, 8);
    float dn = __shfl_xor(den, s, 8);
    float mn = fmaxf(m, mo);
    den = den*__expf(m - mn) + dn*__expf(mo - mn);
    m = mn;
  }
  const float w = 1.0f / (den + 1e-16f);

  // phase 2: weighted gather with precomputed (m, w) — 4 independent chains
  f32x4 acc0 = {0.f,0.f,0.f,0.f}, acc1 = {0.f,0.f,0.f,0.f};
  f32x4 acc2 = {0.f,0.f,0.f,0.f}, acc3 = {0.f,0.f,0.f,0.f};
  int k = 0;
  for (; k+3<d; k+=4){
    int e0 = vcsr[start + k];
    int e1 = vcsr[start + k + 1];
    int e2 = vcsr[start + k + 2];
    int e3 = vcsr[start + k + 3];
    float a0 = alphaE[(size_t)e0*NH + h];
    float a1 = alphaE[(size_t)e1*NH + h];
    float a2 = alphaE[(size_t)e2*NH + h];
    float a3 = alphaE[(size_t)e3*NH + h];
    ushort4 b0 = *(const ushort4*)(Xe + (size_t)e0*HC + cbase);
    ushort4 b1 = *(const ushort4*)(Xe + (size_t)e1*HC + cbase);
    ushort4 b2 = *(const ushort4*)(Xe + (size_t)e2*HC + cbase);
    ushort4 b3 = *(const ushort4*)(Xe + (size_t)e3*HC + cbase);
    acc0 += (__expf(a0 - m) * w) * bf4f(b0);
    acc1 += (__expf(a1 - m) * w) * bf4f(b1);
    acc2 += (__expf(a2 - m) * w) * bf4f(b2);
    acc3 += (__expf(a3 - m) * w) * bf4f(b3);
  }
  for (; k<d; k++){
    int e0 = vcsr[start + k];
    float a0 = alphaE[(size_t)e0*NH + h];
    ushort4 b0 = *(const ushort4*)(Xe + (size_t)e0*HC + cbase);
    acc0 += (__expf(a0 - m) * w) * bf4f(b0);
  }
  acc0 += acc1; acc2 += acc3; acc0 += acc2;
  acc0 += x0;
  __builtin_nontemporal_store(acc0, (f32x4*)(out + obase));
}

extern "C" void kernel_launch(void* const* d_in, const int* in_sizes, int n_in,
                              void* d_out, int out_size, void* d_ws, size_t ws_size,
                              hipStream_t stream){
  const float* X   = (const float*)d_in[0];
  const float* Wm  = (const float*)d_in[1];
  const float* att = (const float*)d_in[2];
  const int* vertex = (const int*)d_in[3];
  const int* edges  = (const int*)d_in[4];
  const int N   = in_sizes[0] / INCH;
  const int NNZ = in_sizes[3];
  const int E   = NEDGE;

  char* ws = (char*)d_ws;
  size_t off = 0;
  auto alloc = [&](size_t bytes)->char*{
    char* p = ws + off;
    off += (bytes + 255) & ~(size_t)255;
    return p;
  };
  unsigned short* Xe     = (unsigned short*)alloc((size_t)E * HC * sizeof(unsigned short)); // 128 MB
  unsigned short* X0bf   = (unsigned short*)alloc((size_t)NN * HC * sizeof(unsigned short)); // 25.6 MB
  float*          score  = (float*)alloc((size_t)NN * NH * sizeof(float));                  // 1.6 MB
  float*          alphaE = (float*)alloc((size_t)E * NH * sizeof(float));
  int*            eoffs  = (int*)alloc((size_t)(E+1) * sizeof(int));
  int*            voffs  = (int*)alloc((size_t)(NN+1) * sizeof(int));
  int*            ecsr   = (int*)alloc((size_t)NNZ * sizeof(int));
  int*            vcsr   = (int*)alloc((size_t)NNZ * sizeof(int));
  int*            cursE  = (int*)alloc(NBE * sizeof(int));
  int*            cursV  = (int*)alloc(NBV * sizeof(int));
  int*            baseE  = (int*)alloc(NBE * sizeof(int));
  int*            baseV  = (int*)alloc(NBV * sizeof(int));
  // staging aliases Xe (dead until edge_agg runs, which is after phase B)
  int2* stgE = (int2*)(void*)Xe;
  int2* stgV = (int2*)((char*)(void*)Xe + (size_t)NBE * CAP_E * sizeof(int2));

  gemm_x0<<<(N + GBM - 1)/GBM, 256, 0, stream>>>(X, Wm, att, X0bf, score, N);
  init_curs<<<1, 512, 0, stream>>>(cursE, cursV);
  phaseA<<<(NNZ + CHUNK_A - 1)/CHUNK_A, 512, 0, stream>>>(vertex, edges, NNZ, cursE, cursV, stgE, stgV);
  bucket_scan<<<1, 512, 0, stream>>>(cursE, cursV, baseE, baseV, eoffs, voffs, NNZ);
  phaseB_k<KE, CAP_E, CAP_E/512><<<NBE, 512, 0, stream>>>(stgE, cursE, baseE, eoffs, ecsr, E);
  phaseB_k<KV, CAP_V, CAP_V/512><<<NBV, 512, 0, stream>>>(stgV, cursV, baseV, voffs, vcsr, NN);
  edge_agg<<<(E + 7)/8, 256, 0, stream>>>(X0bf, score, ecsr, eoffs, Xe, alphaE, E);
  vert_pass<<<(N + 7)/8, 256, 0, stream>>>(X0bf, Xe, alphaE, vcsr, voffs, (float*)d_out, N);
}

// Round 6
// 307.307 us; speedup vs baseline: 1.4014x; 1.0803x over previous
//
#include <hip/hip_runtime.h>
#include <hip/hip_bf16.h>
#include <cstdint>

#define NH 4
#define HC 128     // H*C
#define INCH 128
#define NEDGE 500000
#define NN 100000

// multisplit geometry
#define KE_SHIFT 11            // 2048 edges per bucket
#define KV_SHIFT 9             // 512 vertices per bucket
#define KE (1 << KE_SHIFT)
#define KV (1 << KV_SHIFT)
#define NBE 245                // ceil(500000/2048)
#define NBV 196                // ceil(100000/512)
#define CAP_E 8192             // mean 6554, +20 sigma
#define CAP_V 10240            // mean 8192, +22 sigma
#define CHUNK_A 8192

typedef float          f32x4 __attribute__((ext_vector_type(4)));
typedef float          f32x8 __attribute__((ext_vector_type(8)));
typedef unsigned int   u32x2 __attribute__((ext_vector_type(2)));
typedef unsigned int   u32x4 __attribute__((ext_vector_type(4)));
typedef unsigned short u16x8 __attribute__((ext_vector_type(8)));

static __device__ __forceinline__ unsigned short f2bf(float f){
  union { float f; unsigned u; } v; v.f = f;
  unsigned r = v.u + 0x7fffu + ((v.u >> 16) & 1u);
  return (unsigned short)(r >> 16);
}
static __device__ __forceinline__ float bf2f(unsigned short b){
  union { unsigned u; float f; } v; v.u = ((unsigned)b) << 16;
  return v.f;
}
static __device__ __forceinline__ f32x8 bf8f(u16x8 b){
  f32x8 r;
  r[0]=bf2f(b[0]); r[1]=bf2f(b[1]); r[2]=bf2f(b[2]); r[3]=bf2f(b[3]);
  r[4]=bf2f(b[4]); r[5]=bf2f(b[5]); r[6]=bf2f(b[6]); r[7]=bf2f(b[7]);
  return r;
}

// ---------------- X0bf = bf16(X @ W) + exact att-score ----------------
#define GBM 128
#define GBK 16
__global__ __launch_bounds__(256) void gemm_x0(const float* __restrict__ X,
                                               const float* __restrict__ Wm,
                                               const float* __restrict__ att,
                                               unsigned short* __restrict__ X0bf,
                                               float* __restrict__ score, int nrows){
  __shared__ float As[GBK][GBM+4];
  __shared__ float Bs[GBK][HC+4];
  __shared__ float sc[GBM][17];
  const int tid  = threadIdx.x;
  const int row0 = blockIdx.x * GBM;
  const int trow = tid >> 4;   // 0..15
  const int tcol = tid & 15;   // 0..15
  float acc[8][8];
  #pragma unroll
  for (int i=0;i<8;i++)
    #pragma unroll
    for (int j=0;j<8;j++) acc[i][j]=0.f;

  for (int k0=0;k0<INCH;k0+=GBK){
    #pragma unroll
    for (int l = tid; l < 512; l += 256){
      int r  = l >> 2;
      int ks = (l & 3) * 4;
      int grow = row0 + r;
      float4 v = make_float4(0.f,0.f,0.f,0.f);
      if (grow < nrows) v = *(const float4*)(X + (size_t)grow*INCH + k0 + ks);
      As[ks+0][r]=v.x; As[ks+1][r]=v.y; As[ks+2][r]=v.z; As[ks+3][r]=v.w;
    }
    #pragma unroll
    for (int l = tid; l < 512; l += 256){
      int r  = l >> 5;
      int cs = (l & 31) * 4;
      float4 v = *(const float4*)(Wm + (size_t)(k0+r)*HC + cs);
      *(float4*)(&Bs[r][cs]) = v;
    }
    __syncthreads();
    #pragma unroll
    for (int kk=0;kk<GBK;kk++){
      float a[8], b[8];
      *(float4*)&a[0] = *(float4*)&As[kk][trow*8];
      *(float4*)&a[4] = *(float4*)&As[kk][trow*8+4];
      *(float4*)&b[0] = *(float4*)&Bs[kk][tcol*8];
      *(float4*)&b[4] = *(float4*)&Bs[kk][tcol*8+4];
      #pragma unroll
      for (int i=0;i<8;i++)
        #pragma unroll
        for (int j=0;j<8;j++) acc[i][j] = fmaf(a[i], b[j], acc[i][j]);
    }
    __syncthreads();
  }
  float attv[8];
  *(float4*)&attv[0] = *(const float4*)(att + tcol*8);
  *(float4*)&attv[4] = *(const float4*)(att + tcol*8 + 4);
  #pragma unroll
  for (int i=0;i<8;i++){
    int grow = row0 + trow*8 + i;
    float p = 0.f;
    #pragma unroll
    for (int j=0;j<8;j++) p = fmaf(acc[i][j], attv[j], p);
    sc[trow*8+i][tcol] = p;
    if (grow < nrows){
      ushort4 b0, b1;
      b0.x=f2bf(acc[i][0]); b0.y=f2bf(acc[i][1]); b0.z=f2bf(acc[i][2]); b0.w=f2bf(acc[i][3]);
      b1.x=f2bf(acc[i][4]); b1.y=f2bf(acc[i][5]); b1.z=f2bf(acc[i][6]); b1.w=f2bf(acc[i][7]);
      *(ushort4*)(X0bf + (size_t)grow*HC + tcol*8    ) = b0;   // cached: gathered later
      *(ushort4*)(X0bf + (size_t)grow*HC + tcol*8 + 4) = b1;
    }
  }
  __syncthreads();
  for (int idx = tid; idx < GBM*NH; idx += 256){
    int row = idx >> 2, h = idx & 3;
    int grow = row0 + row;
    if (grow < nrows){
      float s = sc[row][4*h] + sc[row][4*h+1] + sc[row][4*h+2] + sc[row][4*h+3];
      score[(size_t)grow*NH + h] = s;     // cached: tiny + reused
    }
  }
}

// ---------------- CSR build: two-phase LDS-binned multisplit (packed 4B staging) ----------------
__global__ void init_curs(int* __restrict__ cursE, int* __restrict__ cursV){
  int t = threadIdx.x;
  if (t < NBE) cursE[t] = t * CAP_E;
  if (t < NBV) cursV[t] = t * CAP_V;
}

__global__ __launch_bounds__(512) void phaseA(const int* __restrict__ vertex,
                                              const int* __restrict__ edges, int nnz,
                                              int* __restrict__ cursE, int* __restrict__ cursV,
                                              unsigned* __restrict__ stgE, unsigned* __restrict__ stgV){
  __shared__ int cE[NBE], c2E[NBE], gE[NBE];
  __shared__ int cV[NBV], c2V[NBV], gV[NBV];
  const int t = threadIdx.x;
  const int base = blockIdx.x * CHUNK_A;
  int ev[16], vv[16];
  #pragma unroll
  for (int j=0;j<16;j++){
    int i = base + t + j*512;
    if (i < nnz){ ev[j] = edges[i]; vv[j] = vertex[i]; }
    else ev[j] = -1;
  }
  for (int j=t;j<NBE;j+=512){ cE[j]=0; c2E[j]=0; }
  for (int j=t;j<NBV;j+=512){ cV[j]=0; c2V[j]=0; }
  __syncthreads();
  #pragma unroll
  for (int j=0;j<16;j++) if (ev[j]>=0){
    atomicAdd(&cE[ev[j]>>KE_SHIFT], 1);
    atomicAdd(&cV[vv[j]>>KV_SHIFT], 1);
  }
  __syncthreads();
  for (int j=t;j<NBE;j+=512) gE[j] = atomicAdd(&cursE[j], cE[j]);
  for (int j=t;j<NBV;j+=512) gV[j] = atomicAdd(&cursV[j], cV[j]);
  __syncthreads();
  #pragma unroll
  for (int j=0;j<16;j++) if (ev[j]>=0){
    int bE = ev[j]>>KE_SHIFT;
    int p = gE[bE] + atomicAdd(&c2E[bE],1);
    if (p < (bE+1)*CAP_E) stgE[p] = ((unsigned)vv[j] << KE_SHIFT) | (unsigned)(ev[j] & (KE-1));
    int bV = vv[j]>>KV_SHIFT;
    int q = gV[bV] + atomicAdd(&c2V[bV],1);
    if (q < (bV+1)*CAP_V) stgV[q] = ((unsigned)ev[j] << KV_SHIFT) | (unsigned)(vv[j] & (KV-1));
  }
}

__global__ __launch_bounds__(512) void bucket_scan(const int* __restrict__ cursE,
                                                   const int* __restrict__ cursV,
                                                   int* __restrict__ baseE, int* __restrict__ baseV,
                                                   int* __restrict__ eoffs, int* __restrict__ voffs,
                                                   int nnz){
  __shared__ int sh[512];
  const int t = threadIdx.x;
  int v = (t < NBE) ? (cursE[t] - t*CAP_E) : 0;
  sh[t] = v; __syncthreads();
  for (int d2=1; d2<512; d2<<=1){
    int x = (t>=d2) ? sh[t-d2] : 0; __syncthreads();
    sh[t] += x; __syncthreads();
  }
  if (t < NBE) baseE[t] = sh[t] - v;
  __syncthreads();
  int v2 = (t < NBV) ? (cursV[t] - t*CAP_V) : 0;
  sh[t] = v2; __syncthreads();
  for (int d2=1; d2<512; d2<<=1){
    int x = (t>=d2) ? sh[t-d2] : 0; __syncthreads();
    sh[t] += x; __syncthreads();
  }
  if (t < NBV) baseV[t] = sh[t] - v2;
  if (t == 0){ eoffs[NEDGE] = nnz; voffs[NN] = nnz; }
}

template<int K, int CAP, int IT, int SHIFT>
__global__ __launch_bounds__(512) void phaseB_k(const unsigned* __restrict__ stg,
                                                const int* __restrict__ curs,
                                                const int* __restrict__ bbase,
                                                int* __restrict__ offsOut,
                                                int* __restrict__ csrOut, int nKeys){
  __shared__ int cur[K];
  __shared__ int tsum[512];
  const int b = blockIdx.x, t = threadIdx.x;
  const int k0 = b * K;
  const int kc = min(K, nKeys - k0);
  int cnt = curs[b] - b*CAP; cnt = min(cnt, CAP);
  const int gbase = bbase[b];
  unsigned it[IT];
  #pragma unroll
  for (int j=0;j<IT;j++){
    int i = t + j*512;
    it[j] = (i < cnt) ? stg[(size_t)b*CAP + i] : 0xFFFFFFFFu;
  }
  for (int j=t;j<K;j+=512) cur[j] = 0;
  __syncthreads();
  #pragma unroll
  for (int j=0;j<IT;j++) if (it[j] != 0xFFFFFFFFu) atomicAdd(&cur[it[j] & (K-1)], 1);
  __syncthreads();
  constexpr int KPT = K / 512;
  int loc[KPT]; int s = 0;
  #pragma unroll
  for (int j=0;j<KPT;j++){ loc[j] = s; s += cur[t*KPT + j]; }
  tsum[t] = s; __syncthreads();
  for (int d2=1; d2<512; d2<<=1){
    int x = (t>=d2) ? tsum[t-d2] : 0; __syncthreads();
    tsum[t] += x; __syncthreads();
  }
  const int tbase = tsum[t] - s;
  __syncthreads();
  #pragma unroll
  for (int j=0;j<KPT;j++){
    int k = t*KPT + j;
    int abs0 = gbase + tbase + loc[j];
    if (k < kc) offsOut[k0 + k] = abs0;
    cur[k] = abs0;
  }
  __syncthreads();
  #pragma unroll
  for (int j=0;j<IT;j++) if (it[j] != 0xFFFFFFFFu){
    int pos = atomicAdd(&cur[it[j] & (K-1)], 1);
    csrOut[pos] = (int)(it[j] >> SHIFT);
  }
}

// ---------------- per-edge: bf16 mean + score-mean attention (16 lanes/edge, 16B loads) ----------------
__global__ __launch_bounds__(256) void edge_agg(const unsigned short* __restrict__ X0bf,
                                                const float* __restrict__ score,
                                                const int* __restrict__ ecsr,
                                                const int* __restrict__ eoffs,
                                                unsigned short* __restrict__ Xe,
                                                float* __restrict__ alphaE, int E){
  int eg = blockIdx.x * 16 + (threadIdx.x >> 4);
  if (eg >= E) return;
  const int lane  = threadIdx.x & 15;
  const int cbase = lane * 8;
  const int start = eoffs[eg];
  const int d     = eoffs[eg+1] - start;
  f32x8 acc0 = {0.f,0.f,0.f,0.f,0.f,0.f,0.f,0.f};
  f32x8 acc1 = {0.f,0.f,0.f,0.f,0.f,0.f,0.f,0.f};
  float sacc0 = 0.f, sacc1 = 0.f;
  int k = 0;
  for (; k+1<d; k+=2){
    int v0 = ecsr[start + k];
    int v1 = ecsr[start + k + 1];
    u16x8 x0 = *(const u16x8*)(X0bf + (size_t)v0*HC + cbase);
    u16x8 x1 = *(const u16x8*)(X0bf + (size_t)v1*HC + cbase);
    if (lane < NH){
      sacc0 += score[(size_t)v0*NH + lane];
      sacc1 += score[(size_t)v1*NH + lane];
    }
    acc0 += bf8f(x0);
    acc1 += bf8f(x1);
  }
  if (k < d){
    int v0 = ecsr[start + k];
    u16x8 x0 = *(const u16x8*)(X0bf + (size_t)v0*HC + cbase);
    if (lane < NH) sacc0 += score[(size_t)v0*NH + lane];
    acc0 += bf8f(x0);
  }
  acc0 += acc1;
  const float inv = 1.0f / fmaxf((float)d, 1.0f);
  acc0 *= inv;
  u32x4 w;
  w.x = (unsigned)f2bf(acc0[0]) | ((unsigned)f2bf(acc0[1])<<16);
  w.y = (unsigned)f2bf(acc0[2]) | ((unsigned)f2bf(acc0[3])<<16);
  w.z = (unsigned)f2bf(acc0[4]) | ((unsigned)f2bf(acc0[5])<<16);
  w.w = (unsigned)f2bf(acc0[6]) | ((unsigned)f2bf(acc0[7])<<16);
  __builtin_nontemporal_store(w, (u32x4*)(Xe + (size_t)eg*HC + cbase));  // nt: don't evict X0bf
  if (lane < NH){
    float a = (sacc0 + sacc1) * inv;
    a = a > 0.f ? a : 0.01f*a;                        // leaky relu
    __builtin_nontemporal_store(a, alphaE + (size_t)eg*NH + lane);
  }
}

// ---------------- per-vertex: two-phase softmax (16 lanes/vertex, 16B loads) ----------------
__global__ __launch_bounds__(256) void vert_pass(const unsigned short* __restrict__ X0bf,
                                                 const unsigned short* __restrict__ Xe,
                                                 const float* __restrict__ alphaE,
                                                 const int* __restrict__ vcsr,
                                                 const int* __restrict__ voffs,
                                                 float* __restrict__ out, int N){
  int n = blockIdx.x * 16 + (threadIdx.x >> 4);
  if (n >= N) return;
  const int lane  = threadIdx.x & 15;
  const int cbase = lane * 8;
  const int h     = lane >> 2;   // head for this lane's 8 channels
  const int j0    = lane & 3;    // phase-1 edge slot (4-way parallel per head)
  const size_t obase = (size_t)n*HC + cbase;
  f32x8 x0 = bf8f(*(const u16x8*)(X0bf + obase));
  const int start = voffs[n];
  const int d     = voffs[n+1] - start;
  if (d == 0){
    f32x4 lo = {x0[0],x0[1],x0[2],x0[3]}, hi = {x0[4],x0[5],x0[6],x0[7]};
    __builtin_nontemporal_store(lo, (f32x4*)(out + obase));
    __builtin_nontemporal_store(hi, (f32x4*)(out + obase + 4));
    return;
  }

  // phase 1: 4 lanes per head process edges j0, j0+4, ... in parallel
  float m = -1e30f, den = 0.f;
  for (int j=j0; j<d; j+=4){
    int e = vcsr[start + j];
    float a = alphaE[(size_t)e*NH + h];
    float mn = fmaxf(m, a);
    den = den*__expf(m - mn) + __expf(a - mn);
    m = mn;
  }
  #pragma unroll
  for (int s=1; s<4; s<<=1){
    float mo = __shfl_xor(m, s, 4);
    float dn = __shfl_xor(den, s, 4);
    float mn = fmaxf(m, mo);
    den = den*__expf(m - mn) + dn*__expf(mo - mn);
    m = mn;
  }
  const float w = 1.0f / (den + 1e-16f);

  // phase 2: weighted gather with precomputed (m, w) — 4 independent chains
  f32x8 acc0 = {0.f,0.f,0.f,0.f,0.f,0.f,0.f,0.f};
  f32x8 acc1 = {0.f,0.f,0.f,0.f,0.f,0.f,0.f,0.f};
  f32x8 acc2 = {0.f,0.f,0.f,0.f,0.f,0.f,0.f,0.f};
  f32x8 acc3 = {0.f,0.f,0.f,0.f,0.f,0.f,0.f,0.f};
  int k = 0;
  for (; k+3<d; k+=4){
    int e0 = vcsr[start + k];
    int e1 = vcsr[start + k + 1];
    int e2 = vcsr[start + k + 2];
    int e3 = vcsr[start + k + 3];
    float a0 = alphaE[(size_t)e0*NH + h];
    float a1 = alphaE[(size_t)e1*NH + h];
    float a2 = alphaE[(size_t)e2*NH + h];
    float a3 = alphaE[(size_t)e3*NH + h];
    u16x8 b0 = *(const u16x8*)(Xe + (size_t)e0*HC + cbase);
    u16x8 b1 = *(const u16x8*)(Xe + (size_t)e1*HC + cbase);
    u16x8 b2 = *(const u16x8*)(Xe + (size_t)e2*HC + cbase);
    u16x8 b3 = *(const u16x8*)(Xe + (size_t)e3*HC + cbase);
    acc0 += (__expf(a0 - m) * w) * bf8f(b0);
    acc1 += (__expf(a1 - m) * w) * bf8f(b1);
    acc2 += (__expf(a2 - m) * w) * bf8f(b2);
    acc3 += (__expf(a3 - m) * w) * bf8f(b3);
  }
  for (; k<d; k++){
    int e0 = vcsr[start + k];
    float a0 = alphaE[(size_t)e0*NH + h];
    u16x8 b0 = *(const u16x8*)(Xe + (size_t)e0*HC + cbase);
    acc0 += (__expf(a0 - m) * w) * bf8f(b0);
  }
  acc0 += acc1; acc2 += acc3; acc0 += acc2;
  acc0 += x0;
  f32x4 lo = {acc0[0],acc0[1],acc0[2],acc0[3]};
  f32x4 hi = {acc0[4],acc0[5],acc0[6],acc0[7]};
  __builtin_nontemporal_store(lo, (f32x4*)(out + obase));
  __builtin_nontemporal_store(hi, (f32x4*)(out + obase + 4));
}

extern "C" void kernel_launch(void* const* d_in, const int* in_sizes, int n_in,
                              void* d_out, int out_size, void* d_ws, size_t ws_size,
                              hipStream_t stream){
  const float* X   = (const float*)d_in[0];
  const float* Wm  = (const float*)d_in[1];
  const float* att = (const float*)d_in[2];
  const int* vertex = (const int*)d_in[3];
  const int* edges  = (const int*)d_in[4];
  const int N   = in_sizes[0] / INCH;
  const int NNZ = in_sizes[3];
  const int E   = NEDGE;

  char* ws = (char*)d_ws;
  size_t off = 0;
  auto alloc = [&](size_t bytes)->char*{
    char* p = ws + off;
    off += (bytes + 255) & ~(size_t)255;
    return p;
  };
  unsigned short* Xe     = (unsigned short*)alloc((size_t)E * HC * sizeof(unsigned short)); // 128 MB
  unsigned short* X0bf   = (unsigned short*)alloc((size_t)NN * HC * sizeof(unsigned short)); // 25.6 MB
  float*          score  = (float*)alloc((size_t)NN * NH * sizeof(float));                  // 1.6 MB
  float*          alphaE = (float*)alloc((size_t)E * NH * sizeof(float));
  int*            eoffs  = (int*)alloc((size_t)(E+1) * sizeof(int));
  int*            voffs  = (int*)alloc((size_t)(NN+1) * sizeof(int));
  int*            ecsr   = (int*)alloc((size_t)NNZ * sizeof(int));
  int*            vcsr   = (int*)alloc((size_t)NNZ * sizeof(int));
  int*            cursE  = (int*)alloc(NBE * sizeof(int));
  int*            cursV  = (int*)alloc(NBV * sizeof(int));
  int*            baseE  = (int*)alloc(NBE * sizeof(int));
  int*            baseV  = (int*)alloc(NBV * sizeof(int));
  // packed staging aliases Xe (dead until edge_agg runs, which is after phase B)
  unsigned* stgE = (unsigned*)(void*)Xe;
  unsigned* stgV = (unsigned*)((char*)(void*)Xe + (size_t)NBE * CAP_E * sizeof(unsigned));

  gemm_x0<<<(N + GBM - 1)/GBM, 256, 0, stream>>>(X, Wm, att, X0bf, score, N);
  init_curs<<<1, 512, 0, stream>>>(cursE, cursV);
  phaseA<<<(NNZ + CHUNK_A - 1)/CHUNK_A, 512, 0, stream>>>(vertex, edges, NNZ, cursE, cursV, stgE, stgV);
  bucket_scan<<<1, 512, 0, stream>>>(cursE, cursV, baseE, baseV, eoffs, voffs, NNZ);
  phaseB_k<KE, CAP_E, CAP_E/512, KE_SHIFT><<<NBE, 512, 0, stream>>>(stgE, cursE, baseE, eoffs, ecsr, E);
  phaseB_k<KV, CAP_V, CAP_V/512, KV_SHIFT><<<NBV, 512, 0, stream>>>(stgV, cursV, baseV, voffs, vcsr, NN);
  edge_agg<<<(E + 15)/16, 256, 0, stream>>>(X0bf, score, ecsr, eoffs, Xe, alphaE, E);
  vert_pass<<<(N + 15)/16, 256, 0, stream>>>(X0bf, Xe, alphaE, vcsr, voffs, (float*)d_out, N);
}